// Round 1
// baseline (239.041 us; speedup 1.0000x reference)
//
#include <hip/hip_runtime.h>
#include <hip/hip_bf16.h>
#include <stdint.h>

typedef __attribute__((ext_vector_type(4))) float f32x4;
typedef __attribute__((ext_vector_type(2))) float f32x2;
typedef __attribute__((ext_vector_type(8))) __bf16 bf16x8;

__device__ __forceinline__ unsigned short f2bf(float f) {
  unsigned u = __float_as_uint(f);
  unsigned r = (u + 0x7fffu + ((u >> 16) & 1u)) >> 16;
  return (unsigned short)r;
}
__device__ __forceinline__ float bf2f(unsigned short h) {
  return __uint_as_float(((unsigned)h) << 16);
}

__device__ __forceinline__ void load_lds16(const void* g, void* l) {
  __builtin_amdgcn_global_load_lds(
      (const __attribute__((address_space(1))) unsigned int*)g,
      (__attribute__((address_space(3))) unsigned int*)l, 16, 0, 0);
}

// ---------------------------------------------------------------------------
// Kernel 1: weight transpose + bf16 convert.  W0[384][256] -> W0t[256][384],
// W1[256][128] -> W1t[128][256]
__global__ __launch_bounds__(256) void prep_w_kernel(
    const float* __restrict__ W0, const float* __restrict__ W1,
    unsigned short* __restrict__ W0t, unsigned short* __restrict__ W1t) {
  int id = blockIdx.x * 256 + threadIdx.x;
  if (id < 256 * 384) {
    int n = id / 384, k = id - n * 384;
    W0t[id] = f2bf(W0[k * 256 + n]);
  }
  if (id < 128 * 256) {
    int n = id / 256, k = id - n * 256;
    W1t[id] = f2bf(W1[k * 128 + n]);
  }
}

// ---------------------------------------------------------------------------
// Kernel 2: fused three_nn + weighted interp + concat -> X bf16 [65536][384]
__global__ __launch_bounds__(256) void nn_interp_kernel(
    const float* __restrict__ xyz1, const float* __restrict__ xyz2,
    const float* __restrict__ points1, const float* __restrict__ points2,
    unsigned short* __restrict__ X) {
  __shared__ __align__(16) float sx[1024];
  __shared__ __align__(16) float sy[1024];
  __shared__ __align__(16) float sz[1024];
  __shared__ float sw[256][3];
  __shared__ int si[256][3];

  const int b = blockIdx.y;
  const int n0 = blockIdx.x * 256;
  const int tid = threadIdx.x;

  const float* xb = xyz2 + (size_t)b * 1024 * 3;
  for (int i = tid; i < 1024; i += 256) {
    sx[i] = xb[i * 3 + 0];
    sy[i] = xb[i * 3 + 1];
    sz[i] = xb[i * 3 + 2];
  }
  __syncthreads();

  {
    const int n = n0 + tid;
    const float* p = xyz1 + ((size_t)b * 4096 + n) * 3;
    const float px = p[0], py = p[1], pz = p[2];
    float d0 = 3e38f, d1 = 3e38f, d2 = 3e38f;
    int i0 = 0, i1 = 0, i2 = 0;
    const f32x4* vx = (const f32x4*)sx;
    const f32x4* vy = (const f32x4*)sy;
    const f32x4* vz = (const f32x4*)sz;
    for (int j4 = 0; j4 < 256; j4++) {
      f32x4 ax = vx[j4], ay = vy[j4], az = vz[j4];
#pragma unroll
      for (int u = 0; u < 4; u++) {
        float dx = px - ax[u], dy = py - ay[u], dz = pz - az[u];
        float d = dx * dx + dy * dy + dz * dz;
        const int j = j4 * 4 + u;
        if (d < d2) {
          if (d < d1) {
            d2 = d1; i2 = i1;
            if (d < d0) { d1 = d0; i1 = i0; d0 = d; i0 = j; }
            else        { d1 = d; i1 = j; }
          } else { d2 = d; i2 = j; }
        }
      }
    }
    d0 = fmaxf(d0, 1e-10f);
    d1 = fmaxf(d1, 1e-10f);
    d2 = fmaxf(d2, 1e-10f);
    float w0 = 1.f / d0, w1 = 1.f / d1, w2 = 1.f / d2;
    float inv = 1.f / (w0 + w1 + w2);
    sw[tid][0] = w0 * inv; sw[tid][1] = w1 * inv; sw[tid][2] = w2 * inv;
    si[tid][0] = i0; si[tid][1] = i1; si[tid][2] = i2;
  }
  __syncthreads();

  const int wv = tid >> 6, lane = tid & 63;
  const float* p2b = points2 + (size_t)b * 1024 * 256;
  for (int p = 0; p < 64; p++) {
    const int t = wv * 64 + p;
    const int row = b * 4096 + n0 + t;
    const float w0 = sw[t][0], w1 = sw[t][1], w2 = sw[t][2];
    const f32x4* r0 = (const f32x4*)(p2b + (size_t)si[t][0] * 256);
    const f32x4* r1 = (const f32x4*)(p2b + (size_t)si[t][1] * 256);
    const f32x4* r2 = (const f32x4*)(p2b + (size_t)si[t][2] * 256);
    f32x4 a = r0[lane] * w0 + r1[lane] * w1 + r2[lane] * w2;
    unsigned int lo = (unsigned)f2bf(a[0]) | ((unsigned)f2bf(a[1]) << 16);
    unsigned int hi = (unsigned)f2bf(a[2]) | ((unsigned)f2bf(a[3]) << 16);
    *(uint2*)(X + (size_t)row * 384 + lane * 4) = make_uint2(lo, hi);
    const f32x2 q = ((const f32x2*)(points1 + (size_t)row * 128))[lane];
    unsigned int pq = (unsigned)f2bf(q.x) | ((unsigned)f2bf(q.y) << 16);
    *(unsigned int*)(X + (size_t)row * 384 + 256 + lane * 2) = pq;
  }
}

// ---------------------------------------------------------------------------
// GEMM: C[M][N] = A[M][K] * Bt[N][K]^T + bias; also per-col sum/sumsq stats.
// 128x128 tile, BK=32, 4 waves (2x2 of 64x64), mfma 16x16x32 bf16.
template <int KDIM, bool BF16OUT>
__global__ __launch_bounds__(256) void gemm_bn_kernel(
    const unsigned short* __restrict__ A, const unsigned short* __restrict__ Bt,
    const float* __restrict__ bvec, void* __restrict__ Yout,
    float* __restrict__ ssum, float* __restrict__ ssq, const int ldY) {
  __shared__ __align__(16) unsigned short As[128 * 32];
  __shared__ __align__(16) unsigned short Bs[128 * 32];
  const int m0 = blockIdx.x * 128, n0 = blockIdx.y * 128;
  const int tid = threadIdx.x;
  const int wv = tid >> 6, lane = tid & 63;
  const int wm = wv >> 1, wn = wv & 1;
  f32x4 acc[4][4] = {};

  for (int k0 = 0; k0 < KDIM; k0 += 32) {
    __syncthreads();
#pragma unroll
    for (int i = 0; i < 2; i++) {
      const int idx = i * 256 + tid;
      const int r = idx >> 2, kk = (idx & 3) * 8;
      load_lds16(A + (size_t)(m0 + r) * KDIM + k0 + kk, As + i * 2048 + wv * 512);
      load_lds16(Bt + (size_t)(n0 + r) * KDIM + k0 + kk, Bs + i * 2048 + wv * 512);
    }
    __syncthreads();
    bf16x8 af[4], bfr[4];
#pragma unroll
    for (int mf = 0; mf < 4; mf++) {
      const int row = wm * 64 + mf * 16 + (lane & 15);
      af[mf] = *(const bf16x8*)(As + row * 32 + (lane >> 4) * 8);
    }
#pragma unroll
    for (int nf = 0; nf < 4; nf++) {
      const int col = wn * 64 + nf * 16 + (lane & 15);
      bfr[nf] = *(const bf16x8*)(Bs + col * 32 + (lane >> 4) * 8);
    }
#pragma unroll
    for (int mf = 0; mf < 4; mf++)
#pragma unroll
      for (int nf = 0; nf < 4; nf++)
        acc[mf][nf] = __builtin_amdgcn_mfma_f32_16x16x32_bf16(
            af[mf], bfr[nf], acc[mf][nf], 0, 0, 0);
  }

  // Epilogue: +bias, store, per-column stats.
  float s[4] = {0, 0, 0, 0}, s2[4] = {0, 0, 0, 0};
#pragma unroll
  for (int nf = 0; nf < 4; nf++) {
    const int col = n0 + wn * 64 + nf * 16 + (lane & 15);
    const float bv = bvec[col];
#pragma unroll
    for (int mf = 0; mf < 4; mf++) {
      const int rowb = m0 + wm * 64 + mf * 16 + ((lane >> 4) << 2);
      f32x4 v = acc[mf][nf];
#pragma unroll
      for (int r = 0; r < 4; r++) {
        float y = v[r] + bv;
        s[nf] += y;
        s2[nf] += y * y;
        if constexpr (BF16OUT)
          ((unsigned short*)Yout)[(size_t)(rowb + r) * ldY + col] = f2bf(y);
        else
          ((float*)Yout)[(size_t)(rowb + r) * ldY + col] = y;
      }
    }
  }
#pragma unroll
  for (int nf = 0; nf < 4; nf++) {
    s[nf] += __shfl_xor(s[nf], 16, 64);
    s[nf] += __shfl_xor(s[nf], 32, 64);
    s2[nf] += __shfl_xor(s2[nf], 16, 64);
    s2[nf] += __shfl_xor(s2[nf], 32, 64);
  }
  if (lane < 16) {
#pragma unroll
    for (int nf = 0; nf < 4; nf++) {
      const int col = n0 + wn * 64 + nf * 16 + lane;
      atomicAdd(&ssum[col], s[nf]);
      atomicAdd(&ssq[col], s2[nf]);
    }
  }
}

// ---------------------------------------------------------------------------
__global__ void bn_fin_kernel(const float* __restrict__ ssum,
                              const float* __restrict__ ssq,
                              const float* __restrict__ g,
                              const float* __restrict__ be,
                              float* __restrict__ scale,
                              float* __restrict__ bias, int C) {
  int c = blockIdx.x * blockDim.x + threadIdx.x;
  if (c < C) {
    const float invN = 1.0f / 65536.0f;
    float mu = ssum[c] * invN;
    float var = ssq[c] * invN - mu * mu;
    float sc = g[c] * rsqrtf(var + 1e-3f);
    scale[c] = sc;
    bias[c] = be[c] - mu * sc;
  }
}

// In-place BN+ReLU on bf16 [65536][256]
__global__ __launch_bounds__(256) void bnrelu_bf16_kernel(
    unsigned short* __restrict__ Y, const float* __restrict__ scale,
    const float* __restrict__ bias) {
  const size_t i = ((size_t)blockIdx.x * 256 + threadIdx.x) * 8;
  const int c0 = (int)(i & 255);
  uint4 v = *(const uint4*)(Y + i);
  unsigned int w[4] = {v.x, v.y, v.z, v.w};
  unsigned int o[4];
#pragma unroll
  for (int q = 0; q < 4; q++) {
    int c = c0 + q * 2;
    float lo = bf2f((unsigned short)(w[q] & 0xffff));
    float hi = bf2f((unsigned short)(w[q] >> 16));
    lo = fmaxf(0.f, lo * scale[c] + bias[c]);
    hi = fmaxf(0.f, hi * scale[c + 1] + bias[c + 1]);
    o[q] = (unsigned)f2bf(lo) | ((unsigned)f2bf(hi) << 16);
  }
  *(uint4*)(Y + i) = make_uint4(o[0], o[1], o[2], o[3]);
}

// In-place BN+ReLU on fp32 [65536][128] (d_out)
__global__ __launch_bounds__(256) void bnrelu_f32_kernel(
    float* __restrict__ Y, const float* __restrict__ scale,
    const float* __restrict__ bias) {
  const size_t i = ((size_t)blockIdx.x * 256 + threadIdx.x) * 4;
  const int c0 = (int)(i & 127);
  f32x4 v = *(const f32x4*)(Y + i);
#pragma unroll
  for (int q = 0; q < 4; q++) v[q] = fmaxf(0.f, v[q] * scale[c0 + q] + bias[c0 + q]);
  *(f32x4*)(Y + i) = v;
}

// ---------------------------------------------------------------------------
extern "C" void kernel_launch(void* const* d_in, const int* in_sizes, int n_in,
                              void* d_out, int out_size, void* d_ws,
                              size_t ws_size, hipStream_t stream) {
  const float* xyz1 = (const float*)d_in[0];
  const float* points1 = (const float*)d_in[1];
  const float* xyz2 = (const float*)d_in[2];
  const float* points2 = (const float*)d_in[3];
  const float* W0 = (const float*)d_in[4];
  const float* b0 = (const float*)d_in[5];
  const float* g0 = (const float*)d_in[6];
  const float* be0 = (const float*)d_in[7];
  const float* W1 = (const float*)d_in[8];
  const float* b1 = (const float*)d_in[9];
  const float* g1 = (const float*)d_in[10];
  const float* be1 = (const float*)d_in[11];

  char* ws = (char*)d_ws;
  unsigned short* X = (unsigned short*)(ws);                  // 50331648 B
  unsigned short* Y = (unsigned short*)(ws + 50331648);       // 33554432 B
  unsigned short* W0t = (unsigned short*)(ws + 83886080);     // 196608 B
  unsigned short* W1t = (unsigned short*)(ws + 84082688);     // 65536 B
  float* stats = (float*)(ws + 84148224);                     // 6144 B
  float* sum1 = stats, *sq1 = stats + 256, *scale1 = stats + 512, *bias1 = stats + 768;
  float* sum2 = stats + 1024, *sq2 = stats + 1152, *scale2 = stats + 1280, *bias2 = stats + 1408;
  float* outF = (float*)d_out;

  hipMemsetAsync(stats, 0, 1536 * sizeof(float), stream);
  prep_w_kernel<<<384, 256, 0, stream>>>(W0, W1, W0t, W1t);
  nn_interp_kernel<<<dim3(16, 16), 256, 0, stream>>>(xyz1, xyz2, points1, points2, X);
  gemm_bn_kernel<384, true><<<dim3(512, 2), 256, 0, stream>>>(
      X, W0t, b0, (void*)Y, sum1, sq1, 256);
  bn_fin_kernel<<<1, 256, 0, stream>>>(sum1, sq1, g0, be0, scale1, bias1, 256);
  bnrelu_bf16_kernel<<<8192, 256, 0, stream>>>(Y, scale1, bias1);
  gemm_bn_kernel<256, false><<<dim3(512, 1), 256, 0, stream>>>(
      Y, W1t, b1, (void*)outF, sum2, sq2, 128);
  bn_fin_kernel<<<1, 128, 0, stream>>>(sum2, sq2, g1, be1, scale2, bias2, 128);
  bnrelu_f32_kernel<<<8192, 256, 0, stream>>>(outF, scale2, bias2);
}

// Round 2
// 231.012 us; speedup vs baseline: 1.0348x; 1.0348x over previous
//
#include <hip/hip_runtime.h>
#include <hip/hip_bf16.h>
#include <stdint.h>

typedef __attribute__((ext_vector_type(4))) float f32x4;
typedef __attribute__((ext_vector_type(2))) float f32x2;
typedef __attribute__((ext_vector_type(8))) __bf16 bf16x8;

__device__ __forceinline__ unsigned short f2bf(float f) {
  unsigned u = __float_as_uint(f);
  unsigned r = (u + 0x7fffu + ((u >> 16) & 1u)) >> 16;
  return (unsigned short)r;
}
__device__ __forceinline__ float bf2f(unsigned short h) {
  return __uint_as_float(((unsigned)h) << 16);
}

__device__ __forceinline__ void load_lds16(const void* g, void* l) {
  __builtin_amdgcn_global_load_lds(
      (const __attribute__((address_space(1))) unsigned int*)g,
      (__attribute__((address_space(3))) unsigned int*)l, 16, 0, 0);
}

// ---------------------------------------------------------------------------
// Kernel 1: weight transpose + bf16 convert + points2 -> bf16.
__global__ __launch_bounds__(256) void prep_kernel(
    const float* __restrict__ W0, const float* __restrict__ W1,
    const float* __restrict__ P2f, unsigned short* __restrict__ W0t,
    unsigned short* __restrict__ W1t, unsigned short* __restrict__ P2) {
  int id = blockIdx.x * 256 + threadIdx.x;
  if (id < 256 * 384) {
    int n = id / 384, k = id - n * 384;
    W0t[id] = f2bf(W0[k * 256 + n]);
  }
  if (id < 128 * 256) {
    int n = id / 256, k = id - n * 256;
    W1t[id] = f2bf(W1[k * 128 + n]);
  }
  if (id < 1048576) {
    f32x4 v = ((const f32x4*)P2f)[id];
    ushort4 o = make_ushort4(f2bf(v[0]), f2bf(v[1]), f2bf(v[2]), f2bf(v[3]));
    ((ushort4*)P2)[id] = o;
  }
}

// ---------------------------------------------------------------------------
// Kernel 2: three_nn scan. 4 threads per query point, interleaved candidate
// chunks; merge top-3 across the 4 lanes via shuffle. Writes normalized
// weights W3 and absolute gather rows I3.
__global__ __launch_bounds__(256) void three_nn_kernel(
    const float* __restrict__ xyz1, const float* __restrict__ xyz2,
    float* __restrict__ W3, int* __restrict__ I3) {
  __shared__ __align__(16) float sx[1024];
  __shared__ __align__(16) float sy[1024];
  __shared__ __align__(16) float sz[1024];
  const int b = blockIdx.y;
  const int n0 = blockIdx.x * 64;
  const int tid = threadIdx.x;

  const float* xb = xyz2 + (size_t)b * 1024 * 3;
  for (int i = tid; i < 1024; i += 256) {
    sx[i] = xb[i * 3 + 0];
    sy[i] = xb[i * 3 + 1];
    sz[i] = xb[i * 3 + 2];
  }
  __syncthreads();

  const int pt = tid >> 2, q = tid & 3;
  const int n = n0 + pt;
  const float* p = xyz1 + ((size_t)b * 4096 + n) * 3;
  const float px = p[0], py = p[1], pz = p[2];

  float d0 = 3e38f, d1 = 3e38f, d2 = 3e38f;
  int i0 = 0, i1 = 0, i2 = 0;
  auto ins = [&](float e, int j) {
    if (e < d2) {
      if (e < d1) {
        d2 = d1; i2 = i1;
        if (e < d0) { d1 = d0; i1 = i0; d0 = e; i0 = j; }
        else        { d1 = e; i1 = j; }
      } else { d2 = e; i2 = j; }
    }
  };

  const f32x4* vx = (const f32x4*)sx;
  const f32x4* vy = (const f32x4*)sy;
  const f32x4* vz = (const f32x4*)sz;
  for (int jj = 0; jj < 64; jj++) {
    const int c = jj * 4 + q;  // interleaved chunks: wave hits 16 distinct words
    f32x4 ax = vx[c], ay = vy[c], az = vz[c];
#pragma unroll
    for (int u = 0; u < 4; u++) {
      float dx = px - ax[u], dy = py - ay[u], dz = pz - az[u];
      float d = dx * dx + dy * dy + dz * dz;
      ins(d, c * 4 + u);
    }
  }
  // merge across the 4 lanes of this point
#pragma unroll
  for (int off = 1; off <= 2; off <<= 1) {
    float e0 = __shfl_xor(d0, off, 64);
    float e1 = __shfl_xor(d1, off, 64);
    float e2 = __shfl_xor(d2, off, 64);
    int j0 = __shfl_xor(i0, off, 64);
    int j1 = __shfl_xor(i1, off, 64);
    int j2 = __shfl_xor(i2, off, 64);
    ins(e0, j0); ins(e1, j1); ins(e2, j2);
  }

  if (q == 0) {
    d0 = fmaxf(d0, 1e-10f);
    d1 = fmaxf(d1, 1e-10f);
    d2 = fmaxf(d2, 1e-10f);
    float w0 = 1.f / d0, w1 = 1.f / d1, w2 = 1.f / d2;
    float inv = 1.f / (w0 + w1 + w2);
    const int row = b * 4096 + n;
    W3[row * 3 + 0] = w0 * inv;
    W3[row * 3 + 1] = w1 * inv;
    W3[row * 3 + 2] = w2 * inv;
    I3[row * 3 + 0] = (b << 10) + i0;
    I3[row * 3 + 1] = (b << 10) + i1;
    I3[row * 3 + 2] = (b << 10) + i2;
  }
}

// ---------------------------------------------------------------------------
// Kernel 3: gather + weighted interp (bf16 points2) + concat points1 -> X bf16.
// One wave per point-row, 8 rows per wave, 8192 waves.
__global__ __launch_bounds__(256) void interp_concat_kernel(
    const float* __restrict__ points1, const unsigned short* __restrict__ P2,
    const float* __restrict__ W3, const int* __restrict__ I3,
    unsigned short* __restrict__ X) {
  const int gw = blockIdx.x * 4 + (threadIdx.x >> 6);
  const int lane = threadIdx.x & 63;
#pragma unroll 2
  for (int pp = 0; pp < 8; pp++) {
    const int row = gw * 8 + pp;
    const float w0 = W3[row * 3 + 0], w1 = W3[row * 3 + 1], w2 = W3[row * 3 + 2];
    const int g0 = I3[row * 3 + 0], g1 = I3[row * 3 + 1], g2 = I3[row * 3 + 2];
    const ushort4 a0 = *(const ushort4*)(P2 + (size_t)g0 * 256 + lane * 4);
    const ushort4 a1 = *(const ushort4*)(P2 + (size_t)g1 * 256 + lane * 4);
    const ushort4 a2 = *(const ushort4*)(P2 + (size_t)g2 * 256 + lane * 4);
    float o0 = bf2f(a0.x) * w0 + bf2f(a1.x) * w1 + bf2f(a2.x) * w2;
    float o1 = bf2f(a0.y) * w0 + bf2f(a1.y) * w1 + bf2f(a2.y) * w2;
    float o2 = bf2f(a0.z) * w0 + bf2f(a1.z) * w1 + bf2f(a2.z) * w2;
    float o3 = bf2f(a0.w) * w0 + bf2f(a1.w) * w1 + bf2f(a2.w) * w2;
    unsigned int lo = (unsigned)f2bf(o0) | ((unsigned)f2bf(o1) << 16);
    unsigned int hi = (unsigned)f2bf(o2) | ((unsigned)f2bf(o3) << 16);
    *(uint2*)(X + (size_t)row * 384 + lane * 4) = make_uint2(lo, hi);
    const f32x2 qv = ((const f32x2*)(points1 + (size_t)row * 128))[lane];
    unsigned int pq = (unsigned)f2bf(qv.x) | ((unsigned)f2bf(qv.y) << 16);
    *(unsigned int*)(X + (size_t)row * 384 + 256 + lane * 2) = pq;
  }
}

// ---------------------------------------------------------------------------
// GEMM: C[M][N] = A[M][K] * Bt[N][K]^T + bias; also per-col sum/sumsq stats.
// 128x128 tile, BK=32, 4 waves (2x2 of 64x64), mfma 16x16x32 bf16.
template <int KDIM, bool BF16OUT>
__global__ __launch_bounds__(256) void gemm_bn_kernel(
    const unsigned short* __restrict__ A, const unsigned short* __restrict__ Bt,
    const float* __restrict__ bvec, void* __restrict__ Yout,
    float* __restrict__ ssum, float* __restrict__ ssq, const int ldY) {
  __shared__ __align__(16) unsigned short As[128 * 32];
  __shared__ __align__(16) unsigned short Bs[128 * 32];
  const int m0 = blockIdx.x * 128, n0 = blockIdx.y * 128;
  const int tid = threadIdx.x;
  const int wv = tid >> 6, lane = tid & 63;
  const int wm = wv >> 1, wn = wv & 1;
  f32x4 acc[4][4] = {};

  for (int k0 = 0; k0 < KDIM; k0 += 32) {
    __syncthreads();
#pragma unroll
    for (int i = 0; i < 2; i++) {
      const int idx = i * 256 + tid;
      const int r = idx >> 2, kk = (idx & 3) * 8;
      load_lds16(A + (size_t)(m0 + r) * KDIM + k0 + kk, As + i * 2048 + wv * 512);
      load_lds16(Bt + (size_t)(n0 + r) * KDIM + k0 + kk, Bs + i * 2048 + wv * 512);
    }
    __syncthreads();
    bf16x8 af[4], bfr[4];
#pragma unroll
    for (int mf = 0; mf < 4; mf++) {
      const int row = wm * 64 + mf * 16 + (lane & 15);
      af[mf] = *(const bf16x8*)(As + row * 32 + (lane >> 4) * 8);
    }
#pragma unroll
    for (int nf = 0; nf < 4; nf++) {
      const int col = wn * 64 + nf * 16 + (lane & 15);
      bfr[nf] = *(const bf16x8*)(Bs + col * 32 + (lane >> 4) * 8);
    }
#pragma unroll
    for (int mf = 0; mf < 4; mf++)
#pragma unroll
      for (int nf = 0; nf < 4; nf++)
        acc[mf][nf] = __builtin_amdgcn_mfma_f32_16x16x32_bf16(
            af[mf], bfr[nf], acc[mf][nf], 0, 0, 0);
  }

  // Epilogue: +bias, store, per-column stats.
  float s[4] = {0, 0, 0, 0}, s2[4] = {0, 0, 0, 0};
#pragma unroll
  for (int nf = 0; nf < 4; nf++) {
    const int col = n0 + wn * 64 + nf * 16 + (lane & 15);
    const float bv = bvec[col];
#pragma unroll
    for (int mf = 0; mf < 4; mf++) {
      const int rowb = m0 + wm * 64 + mf * 16 + ((lane >> 4) << 2);
      f32x4 v = acc[mf][nf];
#pragma unroll
      for (int r = 0; r < 4; r++) {
        float y = v[r] + bv;
        s[nf] += y;
        s2[nf] += y * y;
        if constexpr (BF16OUT)
          ((unsigned short*)Yout)[(size_t)(rowb + r) * ldY + col] = f2bf(y);
        else
          ((float*)Yout)[(size_t)(rowb + r) * ldY + col] = y;
      }
    }
  }
#pragma unroll
  for (int nf = 0; nf < 4; nf++) {
    s[nf] += __shfl_xor(s[nf], 16, 64);
    s[nf] += __shfl_xor(s[nf], 32, 64);
    s2[nf] += __shfl_xor(s2[nf], 16, 64);
    s2[nf] += __shfl_xor(s2[nf], 32, 64);
  }
  if (lane < 16) {
#pragma unroll
    for (int nf = 0; nf < 4; nf++) {
      const int col = n0 + wn * 64 + nf * 16 + lane;
      atomicAdd(&ssum[col], s[nf]);
      atomicAdd(&ssq[col], s2[nf]);
    }
  }
}

// ---------------------------------------------------------------------------
__global__ void bn_fin_kernel(const float* __restrict__ ssum,
                              const float* __restrict__ ssq,
                              const float* __restrict__ g,
                              const float* __restrict__ be,
                              float* __restrict__ scale,
                              float* __restrict__ bias, int C) {
  int c = blockIdx.x * blockDim.x + threadIdx.x;
  if (c < C) {
    const float invN = 1.0f / 65536.0f;
    float mu = ssum[c] * invN;
    float var = ssq[c] * invN - mu * mu;
    float sc = g[c] * rsqrtf(var + 1e-3f);
    scale[c] = sc;
    bias[c] = be[c] - mu * sc;
  }
}

// In-place BN+ReLU on bf16 [65536][256]
__global__ __launch_bounds__(256) void bnrelu_bf16_kernel(
    unsigned short* __restrict__ Y, const float* __restrict__ scale,
    const float* __restrict__ bias) {
  const size_t i = ((size_t)blockIdx.x * 256 + threadIdx.x) * 8;
  const int c0 = (int)(i & 255);
  uint4 v = *(const uint4*)(Y + i);
  unsigned int w[4] = {v.x, v.y, v.z, v.w};
  unsigned int o[4];
#pragma unroll
  for (int q = 0; q < 4; q++) {
    int c = c0 + q * 2;
    float lo = bf2f((unsigned short)(w[q] & 0xffff));
    float hi = bf2f((unsigned short)(w[q] >> 16));
    lo = fmaxf(0.f, lo * scale[c] + bias[c]);
    hi = fmaxf(0.f, hi * scale[c + 1] + bias[c + 1]);
    o[q] = (unsigned)f2bf(lo) | ((unsigned)f2bf(hi) << 16);
  }
  *(uint4*)(Y + i) = make_uint4(o[0], o[1], o[2], o[3]);
}

// In-place BN+ReLU on fp32 [65536][128] (d_out)
__global__ __launch_bounds__(256) void bnrelu_f32_kernel(
    float* __restrict__ Y, const float* __restrict__ scale,
    const float* __restrict__ bias) {
  const size_t i = ((size_t)blockIdx.x * 256 + threadIdx.x) * 4;
  const int c0 = (int)(i & 127);
  f32x4 v = *(const f32x4*)(Y + i);
#pragma unroll
  for (int q = 0; q < 4; q++) v[q] = fmaxf(0.f, v[q] * scale[c0 + q] + bias[c0 + q]);
  *(f32x4*)(Y + i) = v;
}

// ---------------------------------------------------------------------------
extern "C" void kernel_launch(void* const* d_in, const int* in_sizes, int n_in,
                              void* d_out, int out_size, void* d_ws,
                              size_t ws_size, hipStream_t stream) {
  const float* xyz1 = (const float*)d_in[0];
  const float* points1 = (const float*)d_in[1];
  const float* xyz2 = (const float*)d_in[2];
  const float* points2 = (const float*)d_in[3];
  const float* W0 = (const float*)d_in[4];
  const float* b0 = (const float*)d_in[5];
  const float* g0 = (const float*)d_in[6];
  const float* be0 = (const float*)d_in[7];
  const float* W1 = (const float*)d_in[8];
  const float* b1 = (const float*)d_in[9];
  const float* g1 = (const float*)d_in[10];
  const float* be1 = (const float*)d_in[11];

  char* ws = (char*)d_ws;
  unsigned short* X = (unsigned short*)(ws);              // [65536][384] bf16, 50331648 B
  unsigned short* Y = (unsigned short*)(ws + 50331648);   // [65536][256] bf16, 33554432 B
  // Scratch that dies before GEMM1 writes Y — aliased into the Y region:
  unsigned short* P2 = (unsigned short*)(ws + 50331648);  // 8388608 B (bf16 points2)
  float* W3 = (float*)(ws + 50331648 + 8388608);          // 786432 B
  int* I3 = (int*)(ws + 50331648 + 8388608 + 786432);     // 786432 B (ends < Y end)
  unsigned short* W0t = (unsigned short*)(ws + 83886080); // 196608 B
  unsigned short* W1t = (unsigned short*)(ws + 84082688); // 65536 B
  float* stats = (float*)(ws + 84148224);                 // 6144 B
  float* sum1 = stats, *sq1 = stats + 256, *scale1 = stats + 512, *bias1 = stats + 768;
  float* sum2 = stats + 1024, *sq2 = stats + 1152, *scale2 = stats + 1280, *bias2 = stats + 1408;
  float* outF = (float*)d_out;

  hipMemsetAsync(stats, 0, 1536 * sizeof(float), stream);
  prep_kernel<<<4096, 256, 0, stream>>>(W0, W1, points2, W0t, W1t, P2);
  three_nn_kernel<<<dim3(64, 16), 256, 0, stream>>>(xyz1, xyz2, W3, I3);
  interp_concat_kernel<<<2048, 256, 0, stream>>>(points1, P2, W3, I3, X);
  gemm_bn_kernel<384, true><<<dim3(512, 2), 256, 0, stream>>>(
      X, W0t, b0, (void*)Y, sum1, sq1, 256);
  bn_fin_kernel<<<1, 256, 0, stream>>>(sum1, sq1, g0, be0, scale1, bias1, 256);
  bnrelu_bf16_kernel<<<8192, 256, 0, stream>>>(Y, scale1, bias1);
  gemm_bn_kernel<256, false><<<dim3(512, 1), 256, 0, stream>>>(
      Y, W1t, b1, (void*)outF, sum2, sq2, 128);
  bn_fin_kernel<<<1, 128, 0, stream>>>(sum2, sq2, g1, be1, scale2, bias2, 128);
  bnrelu_f32_kernel<<<8192, 256, 0, stream>>>(outF, scale2, bias2);
}

// Round 3
// 188.130 us; speedup vs baseline: 1.2706x; 1.2279x over previous
//
#include <hip/hip_runtime.h>
#include <hip/hip_bf16.h>
#include <stdint.h>

typedef __attribute__((ext_vector_type(4))) float f32x4;
typedef __attribute__((ext_vector_type(2))) float f32x2;
typedef __attribute__((ext_vector_type(8))) __bf16 bf16x8;

__device__ __forceinline__ unsigned short f2bf(float f) {
  unsigned u = __float_as_uint(f);
  unsigned r = (u + 0x7fffu + ((u >> 16) & 1u)) >> 16;
  return (unsigned short)r;
}
__device__ __forceinline__ float bf2f(unsigned short h) {
  return __uint_as_float(((unsigned)h) << 16);
}

__device__ __forceinline__ void load_lds16(const void* g, void* l) {
  __builtin_amdgcn_global_load_lds(
      (const __attribute__((address_space(1))) unsigned int*)g,
      (__attribute__((address_space(3))) unsigned int*)l, 16, 0, 0);
}

// ---------------------------------------------------------------------------
// Kernel 1: weight transpose + bf16 convert + points2 -> bf16.
__global__ __launch_bounds__(256) void prep_kernel(
    const float* __restrict__ W0, const float* __restrict__ W1,
    const float* __restrict__ P2f, unsigned short* __restrict__ W0t,
    unsigned short* __restrict__ W1t, unsigned short* __restrict__ P2) {
  int id = blockIdx.x * 256 + threadIdx.x;
  if (id < 256 * 384) {
    int n = id / 384, k = id - n * 384;
    W0t[id] = f2bf(W0[k * 256 + n]);
  }
  if (id < 128 * 256) {
    int n = id / 256, k = id - n * 256;
    W1t[id] = f2bf(W1[k * 128 + n]);
  }
  if (id < 1048576) {
    f32x4 v = ((const f32x4*)P2f)[id];
    ushort4 o = make_ushort4(f2bf(v[0]), f2bf(v[1]), f2bf(v[2]), f2bf(v[3]));
    ((ushort4*)P2)[id] = o;
  }
}

// ---------------------------------------------------------------------------
// Kernel 2: three_nn scan. 8 lanes per query point (interleaved candidate
// chunks), branchless top-3 insertion, d' = |a|^2 - 2 p.a (|p|^2 added back
// at the end). 32 points/block, grid 128x16 = 2048 blocks.
__global__ __launch_bounds__(256) void three_nn_kernel(
    const float* __restrict__ xyz1, const float* __restrict__ xyz2,
    float* __restrict__ W3, int* __restrict__ I3) {
  __shared__ __align__(16) float sx[1024];
  __shared__ __align__(16) float sy[1024];
  __shared__ __align__(16) float sz[1024];
  __shared__ __align__(16) float sn[1024];
  const int b = blockIdx.y;
  const int n0 = blockIdx.x * 32;
  const int tid = threadIdx.x;

  const float* xb = xyz2 + (size_t)b * 3072;
  for (int i = tid; i < 1024; i += 256) {
    float x = xb[i * 3 + 0], y = xb[i * 3 + 1], z = xb[i * 3 + 2];
    sx[i] = x; sy[i] = y; sz[i] = z;
    sn[i] = x * x + y * y + z * z;
  }
  __syncthreads();

  const int pt = tid >> 3, q = tid & 7;
  const int n = n0 + pt;
  const float* p = xyz1 + ((size_t)b * 4096 + n) * 3;
  const float px = p[0], py = p[1], pz = p[2];
  const float cx = -2.f * px, cy = -2.f * py, cz = -2.f * pz;

  float d0 = 3e38f, d1 = 3e38f, d2 = 3e38f;
  int i0 = 0, i1 = 0, i2 = 0;
  auto ins = [&](float e, int j) {
    const bool c0 = e < d0, c1 = e < d1, c2 = e < d2;
    const float nd2 = c1 ? d1 : (c2 ? e : d2);
    const int   ni2 = c1 ? i1 : (c2 ? j : i2);
    const float nd1 = c0 ? d0 : (c1 ? e : d1);
    const int   ni1 = c0 ? i0 : (c1 ? j : i1);
    d0 = c0 ? e : d0; i0 = c0 ? j : i0;
    d1 = nd1; i1 = ni1;
    d2 = nd2; i2 = ni2;
  };

  const f32x4* vx = (const f32x4*)sx;
  const f32x4* vy = (const f32x4*)sy;
  const f32x4* vz = (const f32x4*)sz;
  const f32x4* vn = (const f32x4*)sn;
  for (int jj = 0; jj < 32; jj++) {
    const int c = jj * 8 + q;  // wave covers all 32 banks exactly once
    f32x4 ax = vx[c], ay = vy[c], az = vz[c], an = vn[c];
#pragma unroll
    for (int u = 0; u < 4; u++) {
      float d = fmaf(ax[u], cx, fmaf(ay[u], cy, fmaf(az[u], cz, an[u])));
      ins(d, c * 4 + u);
    }
  }
  // merge across the 8 lanes of this point
#pragma unroll
  for (int off = 1; off <= 4; off <<= 1) {
    float e0 = __shfl_xor(d0, off, 64);
    float e1 = __shfl_xor(d1, off, 64);
    float e2 = __shfl_xor(d2, off, 64);
    int j0 = __shfl_xor(i0, off, 64);
    int j1 = __shfl_xor(i1, off, 64);
    int j2 = __shfl_xor(i2, off, 64);
    ins(e0, j0); ins(e1, j1); ins(e2, j2);
  }

  if (q == 0) {
    const float pn = fmaf(px, px, fmaf(py, py, pz * pz));
    float t0 = fmaxf(d0 + pn, 1e-10f);
    float t1 = fmaxf(d1 + pn, 1e-10f);
    float t2 = fmaxf(d2 + pn, 1e-10f);
    float w0 = 1.f / t0, w1 = 1.f / t1, w2 = 1.f / t2;
    float inv = 1.f / (w0 + w1 + w2);
    const int row = b * 4096 + n;
    W3[row * 3 + 0] = w0 * inv;
    W3[row * 3 + 1] = w1 * inv;
    W3[row * 3 + 2] = w2 * inv;
    I3[row * 3 + 0] = (b << 10) + i0;
    I3[row * 3 + 1] = (b << 10) + i1;
    I3[row * 3 + 2] = (b << 10) + i2;
  }
}

// ---------------------------------------------------------------------------
// Kernel 3: gather + weighted interp (bf16 points2) + concat points1 -> X bf16.
// One wave per point-row, 8 rows per wave, 8192 waves.
__global__ __launch_bounds__(256) void interp_concat_kernel(
    const float* __restrict__ points1, const unsigned short* __restrict__ P2,
    const float* __restrict__ W3, const int* __restrict__ I3,
    unsigned short* __restrict__ X) {
  const int gw = blockIdx.x * 4 + (threadIdx.x >> 6);
  const int lane = threadIdx.x & 63;
#pragma unroll 2
  for (int pp = 0; pp < 8; pp++) {
    const int row = gw * 8 + pp;
    const float w0 = W3[row * 3 + 0], w1 = W3[row * 3 + 1], w2 = W3[row * 3 + 2];
    const int g0 = I3[row * 3 + 0], g1 = I3[row * 3 + 1], g2 = I3[row * 3 + 2];
    const ushort4 a0 = *(const ushort4*)(P2 + (size_t)g0 * 256 + lane * 4);
    const ushort4 a1 = *(const ushort4*)(P2 + (size_t)g1 * 256 + lane * 4);
    const ushort4 a2 = *(const ushort4*)(P2 + (size_t)g2 * 256 + lane * 4);
    float o0 = bf2f(a0.x) * w0 + bf2f(a1.x) * w1 + bf2f(a2.x) * w2;
    float o1 = bf2f(a0.y) * w0 + bf2f(a1.y) * w1 + bf2f(a2.y) * w2;
    float o2 = bf2f(a0.z) * w0 + bf2f(a1.z) * w1 + bf2f(a2.z) * w2;
    float o3 = bf2f(a0.w) * w0 + bf2f(a1.w) * w1 + bf2f(a2.w) * w2;
    unsigned int lo = (unsigned)f2bf(o0) | ((unsigned)f2bf(o1) << 16);
    unsigned int hi = (unsigned)f2bf(o2) | ((unsigned)f2bf(o3) << 16);
    *(uint2*)(X + (size_t)row * 384 + lane * 4) = make_uint2(lo, hi);
    const f32x2 qv = ((const f32x2*)(points1 + (size_t)row * 128))[lane];
    unsigned int pq = (unsigned)f2bf(qv.x) | ((unsigned)f2bf(qv.y) << 16);
    *(unsigned int*)(X + (size_t)row * 384 + 256 + lane * 2) = pq;
  }
}

// ---------------------------------------------------------------------------
// GEMM: C[M][N] = A[M][K] * Bt[N][K]^T + bias; also per-col sum/sumsq stats.
// 128x128 tile, BK=32, 4 waves (2x2 of 64x64), mfma 16x16x32 bf16.
template <int KDIM, bool BF16OUT>
__global__ __launch_bounds__(256) void gemm_bn_kernel(
    const unsigned short* __restrict__ A, const unsigned short* __restrict__ Bt,
    const float* __restrict__ bvec, void* __restrict__ Yout,
    float* __restrict__ ssum, float* __restrict__ ssq, const int ldY) {
  __shared__ __align__(16) unsigned short As[128 * 32];
  __shared__ __align__(16) unsigned short Bs[128 * 32];
  const int m0 = blockIdx.x * 128, n0 = blockIdx.y * 128;
  const int tid = threadIdx.x;
  const int wv = tid >> 6, lane = tid & 63;
  const int wm = wv >> 1, wn = wv & 1;
  f32x4 acc[4][4] = {};

  for (int k0 = 0; k0 < KDIM; k0 += 32) {
    __syncthreads();
#pragma unroll
    for (int i = 0; i < 2; i++) {
      const int idx = i * 256 + tid;
      const int r = idx >> 2, kk = (idx & 3) * 8;
      load_lds16(A + (size_t)(m0 + r) * KDIM + k0 + kk, As + i * 2048 + wv * 512);
      load_lds16(Bt + (size_t)(n0 + r) * KDIM + k0 + kk, Bs + i * 2048 + wv * 512);
    }
    __syncthreads();
    bf16x8 af[4], bfr[4];
#pragma unroll
    for (int mf = 0; mf < 4; mf++) {
      const int row = wm * 64 + mf * 16 + (lane & 15);
      af[mf] = *(const bf16x8*)(As + row * 32 + (lane >> 4) * 8);
    }
#pragma unroll
    for (int nf = 0; nf < 4; nf++) {
      const int col = wn * 64 + nf * 16 + (lane & 15);
      bfr[nf] = *(const bf16x8*)(Bs + col * 32 + (lane >> 4) * 8);
    }
#pragma unroll
    for (int mf = 0; mf < 4; mf++)
#pragma unroll
      for (int nf = 0; nf < 4; nf++)
        acc[mf][nf] = __builtin_amdgcn_mfma_f32_16x16x32_bf16(
            af[mf], bfr[nf], acc[mf][nf], 0, 0, 0);
  }

  // Epilogue: +bias, store, per-column stats.
  float s[4] = {0, 0, 0, 0}, s2[4] = {0, 0, 0, 0};
#pragma unroll
  for (int nf = 0; nf < 4; nf++) {
    const int col = n0 + wn * 64 + nf * 16 + (lane & 15);
    const float bv = bvec[col];
#pragma unroll
    for (int mf = 0; mf < 4; mf++) {
      const int rowb = m0 + wm * 64 + mf * 16 + ((lane >> 4) << 2);
      f32x4 v = acc[mf][nf];
#pragma unroll
      for (int r = 0; r < 4; r++) {
        float y = v[r] + bv;
        s[nf] += y;
        s2[nf] += y * y;
        if constexpr (BF16OUT)
          ((unsigned short*)Yout)[(size_t)(rowb + r) * ldY + col] = f2bf(y);
        else
          ((float*)Yout)[(size_t)(rowb + r) * ldY + col] = y;
      }
    }
  }
#pragma unroll
  for (int nf = 0; nf < 4; nf++) {
    s[nf] += __shfl_xor(s[nf], 16, 64);
    s[nf] += __shfl_xor(s[nf], 32, 64);
    s2[nf] += __shfl_xor(s2[nf], 16, 64);
    s2[nf] += __shfl_xor(s2[nf], 32, 64);
  }
  if (lane < 16) {
#pragma unroll
    for (int nf = 0; nf < 4; nf++) {
      const int col = n0 + wn * 64 + nf * 16 + lane;
      atomicAdd(&ssum[col], s[nf]);
      atomicAdd(&ssq[col], s2[nf]);
    }
  }
}

// ---------------------------------------------------------------------------
__global__ void bn_fin_kernel(const float* __restrict__ ssum,
                              const float* __restrict__ ssq,
                              const float* __restrict__ g,
                              const float* __restrict__ be,
                              float* __restrict__ scale,
                              float* __restrict__ bias, int C) {
  int c = blockIdx.x * blockDim.x + threadIdx.x;
  if (c < C) {
    const float invN = 1.0f / 65536.0f;
    float mu = ssum[c] * invN;
    float var = ssq[c] * invN - mu * mu;
    float sc = g[c] * rsqrtf(var + 1e-3f);
    scale[c] = sc;
    bias[c] = be[c] - mu * sc;
  }
}

// In-place BN+ReLU on bf16 [65536][256]
__global__ __launch_bounds__(256) void bnrelu_bf16_kernel(
    unsigned short* __restrict__ Y, const float* __restrict__ scale,
    const float* __restrict__ bias) {
  const size_t i = ((size_t)blockIdx.x * 256 + threadIdx.x) * 8;
  const int c0 = (int)(i & 255);
  uint4 v = *(const uint4*)(Y + i);
  unsigned int w[4] = {v.x, v.y, v.z, v.w};
  unsigned int o[4];
#pragma unroll
  for (int q = 0; q < 4; q++) {
    int c = c0 + q * 2;
    float lo = bf2f((unsigned short)(w[q] & 0xffff));
    float hi = bf2f((unsigned short)(w[q] >> 16));
    lo = fmaxf(0.f, lo * scale[c] + bias[c]);
    hi = fmaxf(0.f, hi * scale[c + 1] + bias[c + 1]);
    o[q] = (unsigned)f2bf(lo) | ((unsigned)f2bf(hi) << 16);
  }
  *(uint4*)(Y + i) = make_uint4(o[0], o[1], o[2], o[3]);
}

// In-place BN+ReLU on fp32 [65536][128] (d_out)
__global__ __launch_bounds__(256) void bnrelu_f32_kernel(
    float* __restrict__ Y, const float* __restrict__ scale,
    const float* __restrict__ bias) {
  const size_t i = ((size_t)blockIdx.x * 256 + threadIdx.x) * 4;
  const int c0 = (int)(i & 127);
  f32x4 v = *(const f32x4*)(Y + i);
#pragma unroll
  for (int q = 0; q < 4; q++) v[q] = fmaxf(0.f, v[q] * scale[c0 + q] + bias[c0 + q]);
  *(f32x4*)(Y + i) = v;
}

// ---------------------------------------------------------------------------
extern "C" void kernel_launch(void* const* d_in, const int* in_sizes, int n_in,
                              void* d_out, int out_size, void* d_ws,
                              size_t ws_size, hipStream_t stream) {
  const float* xyz1 = (const float*)d_in[0];
  const float* points1 = (const float*)d_in[1];
  const float* xyz2 = (const float*)d_in[2];
  const float* points2 = (const float*)d_in[3];
  const float* W0 = (const float*)d_in[4];
  const float* b0 = (const float*)d_in[5];
  const float* g0 = (const float*)d_in[6];
  const float* be0 = (const float*)d_in[7];
  const float* W1 = (const float*)d_in[8];
  const float* b1 = (const float*)d_in[9];
  const float* g1 = (const float*)d_in[10];
  const float* be1 = (const float*)d_in[11];

  char* ws = (char*)d_ws;
  unsigned short* X = (unsigned short*)(ws);              // [65536][384] bf16, 50331648 B
  unsigned short* Y = (unsigned short*)(ws + 50331648);   // [65536][256] bf16, 33554432 B
  // Scratch that dies before GEMM1 writes Y — aliased into the Y region:
  unsigned short* P2 = (unsigned short*)(ws + 50331648);  // 8388608 B (bf16 points2)
  float* W3 = (float*)(ws + 50331648 + 8388608);          // 786432 B
  int* I3 = (int*)(ws + 50331648 + 8388608 + 786432);     // 786432 B (ends < Y end)
  unsigned short* W0t = (unsigned short*)(ws + 83886080); // 196608 B
  unsigned short* W1t = (unsigned short*)(ws + 84082688); // 65536 B
  float* stats = (float*)(ws + 84148224);                 // 6144 B
  float* sum1 = stats, *sq1 = stats + 256, *scale1 = stats + 512, *bias1 = stats + 768;
  float* sum2 = stats + 1024, *sq2 = stats + 1152, *scale2 = stats + 1280, *bias2 = stats + 1408;
  float* outF = (float*)d_out;

  hipMemsetAsync(stats, 0, 1536 * sizeof(float), stream);
  prep_kernel<<<4096, 256, 0, stream>>>(W0, W1, points2, W0t, W1t, P2);
  three_nn_kernel<<<dim3(128, 16), 256, 0, stream>>>(xyz1, xyz2, W3, I3);
  interp_concat_kernel<<<2048, 256, 0, stream>>>(points1, P2, W3, I3, X);
  gemm_bn_kernel<384, true><<<dim3(512, 2), 256, 0, stream>>>(
      X, W0t, b0, (void*)Y, sum1, sq1, 256);
  bn_fin_kernel<<<1, 256, 0, stream>>>(sum1, sq1, g0, be0, scale1, bias1, 256);
  bnrelu_bf16_kernel<<<8192, 256, 0, stream>>>(Y, scale1, bias1);
  gemm_bn_kernel<256, false><<<dim3(512, 1), 256, 0, stream>>>(
      Y, W1t, b1, (void*)outF, sum2, sq2, 128);
  bn_fin_kernel<<<1, 128, 0, stream>>>(sum2, sq2, g1, be1, scale2, bias2, 128);
  bnrelu_f32_kernel<<<8192, 256, 0, stream>>>(outF, scale2, bias2);
}

// Round 4
// 161.173 us; speedup vs baseline: 1.4831x; 1.1673x over previous
//
#include <hip/hip_runtime.h>
#include <hip/hip_bf16.h>
#include <stdint.h>

typedef __attribute__((ext_vector_type(4))) float f32x4;
typedef __attribute__((ext_vector_type(2))) float f32x2;
typedef __attribute__((ext_vector_type(8))) __bf16 bf16x8;

__device__ __forceinline__ unsigned short f2bf(float f) {
  unsigned u = __float_as_uint(f);
  unsigned r = (u + 0x7fffu + ((u >> 16) & 1u)) >> 16;
  return (unsigned short)r;
}
__device__ __forceinline__ float bf2f(unsigned short h) {
  return __uint_as_float(((unsigned)h) << 16);
}

__device__ __forceinline__ void load_lds16(const void* g, void* l) {
  __builtin_amdgcn_global_load_lds(
      (const __attribute__((address_space(1))) unsigned int*)g,
      (__attribute__((address_space(3))) unsigned int*)l, 16, 0, 0);
}

// ---------------------------------------------------------------------------
// Kernel 1: weight transpose + bf16 convert + points2 -> bf16.
__global__ __launch_bounds__(256) void prep_kernel(
    const float* __restrict__ W0, const float* __restrict__ W1,
    const float* __restrict__ P2f, unsigned short* __restrict__ W0t,
    unsigned short* __restrict__ W1t, unsigned short* __restrict__ P2) {
  int id = blockIdx.x * 256 + threadIdx.x;
  if (id < 256 * 384) {
    int n = id / 384, k = id - n * 384;
    W0t[id] = f2bf(W0[k * 256 + n]);
  }
  if (id < 128 * 256) {
    int n = id / 256, k = id - n * 256;
    W1t[id] = f2bf(W1[k * 128 + n]);
  }
  if (id < 1048576) {
    f32x4 v = ((const f32x4*)P2f)[id];
    ushort4 o = make_ushort4(f2bf(v[0]), f2bf(v[1]), f2bf(v[2]), f2bf(v[3]));
    ((ushort4*)P2)[id] = o;
  }
}

// ---------------------------------------------------------------------------
// Kernel 2: three_nn scan. 8 lanes per query point, branchless top-3,
// d' = |a|^2 - 2 p.a.
__global__ __launch_bounds__(256) void three_nn_kernel(
    const float* __restrict__ xyz1, const float* __restrict__ xyz2,
    float* __restrict__ W3, int* __restrict__ I3) {
  __shared__ __align__(16) float sx[1024];
  __shared__ __align__(16) float sy[1024];
  __shared__ __align__(16) float sz[1024];
  __shared__ __align__(16) float sn[1024];
  const int b = blockIdx.y;
  const int n0 = blockIdx.x * 32;
  const int tid = threadIdx.x;

  const float* xb = xyz2 + (size_t)b * 3072;
  for (int i = tid; i < 1024; i += 256) {
    float x = xb[i * 3 + 0], y = xb[i * 3 + 1], z = xb[i * 3 + 2];
    sx[i] = x; sy[i] = y; sz[i] = z;
    sn[i] = x * x + y * y + z * z;
  }
  __syncthreads();

  const int pt = tid >> 3, q = tid & 7;
  const int n = n0 + pt;
  const float* p = xyz1 + ((size_t)b * 4096 + n) * 3;
  const float px = p[0], py = p[1], pz = p[2];
  const float cx = -2.f * px, cy = -2.f * py, cz = -2.f * pz;

  float d0 = 3e38f, d1 = 3e38f, d2 = 3e38f;
  int i0 = 0, i1 = 0, i2 = 0;
  auto ins = [&](float e, int j) {
    const bool c0 = e < d0, c1 = e < d1, c2 = e < d2;
    const float nd2 = c1 ? d1 : (c2 ? e : d2);
    const int   ni2 = c1 ? i1 : (c2 ? j : i2);
    const float nd1 = c0 ? d0 : (c1 ? e : d1);
    const int   ni1 = c0 ? i0 : (c1 ? j : i1);
    d0 = c0 ? e : d0; i0 = c0 ? j : i0;
    d1 = nd1; i1 = ni1;
    d2 = nd2; i2 = ni2;
  };

  const f32x4* vx = (const f32x4*)sx;
  const f32x4* vy = (const f32x4*)sy;
  const f32x4* vz = (const f32x4*)sz;
  const f32x4* vn = (const f32x4*)sn;
  for (int jj = 0; jj < 32; jj++) {
    const int c = jj * 8 + q;
    f32x4 ax = vx[c], ay = vy[c], az = vz[c], an = vn[c];
#pragma unroll
    for (int u = 0; u < 4; u++) {
      float d = fmaf(ax[u], cx, fmaf(ay[u], cy, fmaf(az[u], cz, an[u])));
      ins(d, c * 4 + u);
    }
  }
#pragma unroll
  for (int off = 1; off <= 4; off <<= 1) {
    float e0 = __shfl_xor(d0, off, 64);
    float e1 = __shfl_xor(d1, off, 64);
    float e2 = __shfl_xor(d2, off, 64);
    int j0 = __shfl_xor(i0, off, 64);
    int j1 = __shfl_xor(i1, off, 64);
    int j2 = __shfl_xor(i2, off, 64);
    ins(e0, j0); ins(e1, j1); ins(e2, j2);
  }

  if (q == 0) {
    const float pn = fmaf(px, px, fmaf(py, py, pz * pz));
    float t0 = fmaxf(d0 + pn, 1e-10f);
    float t1 = fmaxf(d1 + pn, 1e-10f);
    float t2 = fmaxf(d2 + pn, 1e-10f);
    float w0 = 1.f / t0, w1 = 1.f / t1, w2 = 1.f / t2;
    float inv = 1.f / (w0 + w1 + w2);
    const int row = b * 4096 + n;
    W3[row * 3 + 0] = w0 * inv;
    W3[row * 3 + 1] = w1 * inv;
    W3[row * 3 + 2] = w2 * inv;
    I3[row * 3 + 0] = (b << 10) + i0;
    I3[row * 3 + 1] = (b << 10) + i1;
    I3[row * 3 + 2] = (b << 10) + i2;
  }
}

// ---------------------------------------------------------------------------
// Kernel 3: gather + weighted interp + concat -> X bf16 [65536][384]
__global__ __launch_bounds__(256) void interp_concat_kernel(
    const float* __restrict__ points1, const unsigned short* __restrict__ P2,
    const float* __restrict__ W3, const int* __restrict__ I3,
    unsigned short* __restrict__ X) {
  const int gw = blockIdx.x * 4 + (threadIdx.x >> 6);
  const int lane = threadIdx.x & 63;
#pragma unroll 2
  for (int pp = 0; pp < 8; pp++) {
    const int row = gw * 8 + pp;
    const float w0 = W3[row * 3 + 0], w1 = W3[row * 3 + 1], w2 = W3[row * 3 + 2];
    const int g0 = I3[row * 3 + 0], g1 = I3[row * 3 + 1], g2 = I3[row * 3 + 2];
    const ushort4 a0 = *(const ushort4*)(P2 + (size_t)g0 * 256 + lane * 4);
    const ushort4 a1 = *(const ushort4*)(P2 + (size_t)g1 * 256 + lane * 4);
    const ushort4 a2 = *(const ushort4*)(P2 + (size_t)g2 * 256 + lane * 4);
    float o0 = bf2f(a0.x) * w0 + bf2f(a1.x) * w1 + bf2f(a2.x) * w2;
    float o1 = bf2f(a0.y) * w0 + bf2f(a1.y) * w1 + bf2f(a2.y) * w2;
    float o2 = bf2f(a0.z) * w0 + bf2f(a1.z) * w1 + bf2f(a2.z) * w2;
    float o3 = bf2f(a0.w) * w0 + bf2f(a1.w) * w1 + bf2f(a2.w) * w2;
    unsigned int lo = (unsigned)f2bf(o0) | ((unsigned)f2bf(o1) << 16);
    unsigned int hi = (unsigned)f2bf(o2) | ((unsigned)f2bf(o3) << 16);
    *(uint2*)(X + (size_t)row * 384 + lane * 4) = make_uint2(lo, hi);
    const f32x2 qv = ((const f32x2*)(points1 + (size_t)row * 128))[lane];
    unsigned int pq = (unsigned)f2bf(qv.x) | ((unsigned)f2bf(qv.y) << 16);
    *(unsigned int*)(X + (size_t)row * 384 + 256 + lane * 2) = pq;
  }
}

// ---------------------------------------------------------------------------
// GEMM1: [65536][384] x [384][256] + b0 -> Y bf16 (pre-BN) + col stats.
// Tile 128x256 (N fused), 8 waves (2m x 4n of 64x64), BK=32, double-buffered.
__global__ __launch_bounds__(512) void gemm1_kernel(
    const unsigned short* __restrict__ A, const unsigned short* __restrict__ Bt,
    const float* __restrict__ bvec, unsigned short* __restrict__ Y,
    float* __restrict__ ssum, float* __restrict__ ssq) {
  __shared__ __align__(16) unsigned short As[2][128 * 32];
  __shared__ __align__(16) unsigned short Bs[2][256 * 32];
  const int m0 = blockIdx.x * 128;
  const int tid = threadIdx.x;
  const int wv = tid >> 6, lane = tid & 63;
  const int wm = wv >> 2, wn = wv & 3;
  const int arow = tid >> 2, akoff = (tid & 3) * 8;
  f32x4 acc[4][4] = {};

  auto stage = [&](int k0, int s) {
    load_lds16(A + (size_t)(m0 + arow) * 384 + k0 + akoff, &As[s][wv * 512]);
    load_lds16(Bt + (size_t)arow * 384 + k0 + akoff, &Bs[s][wv * 512]);
    load_lds16(Bt + (size_t)(arow + 128) * 384 + k0 + akoff,
               &Bs[s][4096 + wv * 512]);
  };

  stage(0, 0);
  __syncthreads();
  for (int t = 0; t < 12; t++) {
    const int cur = t & 1;
    if (t < 11) stage((t + 1) * 32, cur ^ 1);
    bf16x8 af[4], bfr[4];
#pragma unroll
    for (int mf = 0; mf < 4; mf++) {
      const int row = wm * 64 + mf * 16 + (lane & 15);
      af[mf] = *(const bf16x8*)&As[cur][row * 32 + (lane >> 4) * 8];
    }
#pragma unroll
    for (int nf = 0; nf < 4; nf++) {
      const int col = wn * 64 + nf * 16 + (lane & 15);
      bfr[nf] = *(const bf16x8*)&Bs[cur][col * 32 + (lane >> 4) * 8];
    }
#pragma unroll
    for (int mf = 0; mf < 4; mf++)
#pragma unroll
      for (int nf = 0; nf < 4; nf++)
        acc[mf][nf] = __builtin_amdgcn_mfma_f32_16x16x32_bf16(
            af[mf], bfr[nf], acc[mf][nf], 0, 0, 0);
    if (t < 11) __syncthreads();
  }

  float s[4] = {0, 0, 0, 0}, s2[4] = {0, 0, 0, 0};
#pragma unroll
  for (int nf = 0; nf < 4; nf++) {
    const int col = wn * 64 + nf * 16 + (lane & 15);
    const float bv = bvec[col];
#pragma unroll
    for (int mf = 0; mf < 4; mf++) {
      const int rowb = m0 + wm * 64 + mf * 16 + ((lane >> 4) << 2);
      f32x4 v = acc[mf][nf];
#pragma unroll
      for (int r = 0; r < 4; r++) {
        float y = v[r] + bv;
        s[nf] += y;
        s2[nf] += y * y;
        Y[(size_t)(rowb + r) * 256 + col] = f2bf(y);
      }
    }
  }
#pragma unroll
  for (int nf = 0; nf < 4; nf++) {
    s[nf] += __shfl_xor(s[nf], 16, 64);
    s[nf] += __shfl_xor(s[nf], 32, 64);
    s2[nf] += __shfl_xor(s2[nf], 16, 64);
    s2[nf] += __shfl_xor(s2[nf], 32, 64);
  }
  if (lane < 16) {
#pragma unroll
    for (int nf = 0; nf < 4; nf++) {
      const int col = wn * 64 + nf * 16 + lane;
      atomicAdd(&ssum[col], s[nf]);
      atomicAdd(&ssq[col], s2[nf]);
    }
  }
}

// ---------------------------------------------------------------------------
// GEMM2: A = relu(BN1(Y)) applied on the fly during reg-staging;
// [65536][256] x [256][128] + b1 -> Y2 bf16 (pre-BN2) + col stats.
// Tile 128x128 (N fused), 4 waves (2x2 of 64x64), BK=32, double-buffered.
__device__ __forceinline__ uint4 bnpack(bf16x8 r, const float* __restrict__ sc,
                                        const float* __restrict__ bi) {
  unsigned short o[8];
#pragma unroll
  for (int j = 0; j < 8; j++) {
    float v = (float)r[j];
    v = fmaxf(0.f, fmaf(v, sc[j], bi[j]));
    o[j] = f2bf(v);
  }
  return make_uint4((unsigned)o[0] | ((unsigned)o[1] << 16),
                    (unsigned)o[2] | ((unsigned)o[3] << 16),
                    (unsigned)o[4] | ((unsigned)o[5] << 16),
                    (unsigned)o[6] | ((unsigned)o[7] << 16));
}

__global__ __launch_bounds__(256) void gemm2_kernel(
    const unsigned short* __restrict__ Yin, const unsigned short* __restrict__ Bt,
    const float* __restrict__ scale1, const float* __restrict__ bias1,
    const float* __restrict__ bvec, unsigned short* __restrict__ Y2,
    float* __restrict__ ssum, float* __restrict__ ssq) {
  __shared__ __align__(16) unsigned short As[2][128 * 32];
  __shared__ __align__(16) unsigned short Bs[2][128 * 32];
  const int m0 = blockIdx.x * 128;
  const int tid = threadIdx.x;
  const int wv = tid >> 6, lane = tid & 63;
  const int wm = wv >> 1, wn = wv & 1;
  const int arow = tid >> 2, akoff = (tid & 3) * 8;  // arow 0..63
  f32x4 acc[4][4] = {};

  auto regloadA = [&](int k0, bf16x8& r0, bf16x8& r1) {
    r0 = *(const bf16x8*)(Yin + (size_t)(m0 + arow) * 256 + k0 + akoff);
    r1 = *(const bf16x8*)(Yin + (size_t)(m0 + arow + 64) * 256 + k0 + akoff);
  };
  auto stageB = [&](int k0, int s) {
    load_lds16(Bt + (size_t)arow * 256 + k0 + akoff, &Bs[s][wv * 512]);
    load_lds16(Bt + (size_t)(arow + 64) * 256 + k0 + akoff,
               &Bs[s][2048 + wv * 512]);
  };
  auto bnwrite = [&](int k0, bf16x8 r0, bf16x8 r1, int s) {
    const float* sc = scale1 + k0 + akoff;
    const float* bi = bias1 + k0 + akoff;
    *(uint4*)&As[s][tid * 8] = bnpack(r0, sc, bi);
    *(uint4*)&As[s][2048 + tid * 8] = bnpack(r1, sc, bi);
  };

  bf16x8 ar0, ar1;
  regloadA(0, ar0, ar1);
  stageB(0, 0);
  bnwrite(0, ar0, ar1, 0);
  __syncthreads();

  for (int t = 0; t < 8; t++) {
    const int cur = t & 1;
    if (t < 7) {
      regloadA((t + 1) * 32, ar0, ar1);
      stageB((t + 1) * 32, cur ^ 1);
    }
    bf16x8 af[4], bfr[4];
#pragma unroll
    for (int mf = 0; mf < 4; mf++) {
      const int row = wm * 64 + mf * 16 + (lane & 15);
      af[mf] = *(const bf16x8*)&As[cur][row * 32 + (lane >> 4) * 8];
    }
#pragma unroll
    for (int nf = 0; nf < 4; nf++) {
      const int col = wn * 64 + nf * 16 + (lane & 15);
      bfr[nf] = *(const bf16x8*)&Bs[cur][col * 32 + (lane >> 4) * 8];
    }
#pragma unroll
    for (int mf = 0; mf < 4; mf++)
#pragma unroll
      for (int nf = 0; nf < 4; nf++)
        acc[mf][nf] = __builtin_amdgcn_mfma_f32_16x16x32_bf16(
            af[mf], bfr[nf], acc[mf][nf], 0, 0, 0);
    if (t < 7) {
      bnwrite((t + 1) * 32, ar0, ar1, cur ^ 1);
      __syncthreads();
    }
  }

  float s[4] = {0, 0, 0, 0}, s2[4] = {0, 0, 0, 0};
#pragma unroll
  for (int nf = 0; nf < 4; nf++) {
    const int col = wn * 64 + nf * 16 + (lane & 15);
    const float bv = bvec[col];
#pragma unroll
    for (int mf = 0; mf < 4; mf++) {
      const int rowb = m0 + wm * 64 + mf * 16 + ((lane >> 4) << 2);
      f32x4 v = acc[mf][nf];
#pragma unroll
      for (int r = 0; r < 4; r++) {
        float y = v[r] + bv;
        s[nf] += y;
        s2[nf] += y * y;
        Y2[(size_t)(rowb + r) * 128 + col] = f2bf(y);
      }
    }
  }
#pragma unroll
  for (int nf = 0; nf < 4; nf++) {
    s[nf] += __shfl_xor(s[nf], 16, 64);
    s[nf] += __shfl_xor(s[nf], 32, 64);
    s2[nf] += __shfl_xor(s2[nf], 16, 64);
    s2[nf] += __shfl_xor(s2[nf], 32, 64);
  }
  if (lane < 16) {
#pragma unroll
    for (int nf = 0; nf < 4; nf++) {
      const int col = wn * 64 + nf * 16 + lane;
      atomicAdd(&ssum[col], s[nf]);
      atomicAdd(&ssq[col], s2[nf]);
    }
  }
}

// ---------------------------------------------------------------------------
__global__ void bn_fin_kernel(const float* __restrict__ ssum,
                              const float* __restrict__ ssq,
                              const float* __restrict__ g,
                              const float* __restrict__ be,
                              float* __restrict__ scale,
                              float* __restrict__ bias, int C) {
  int c = blockIdx.x * blockDim.x + threadIdx.x;
  if (c < C) {
    const float invN = 1.0f / 65536.0f;
    float mu = ssum[c] * invN;
    float var = ssq[c] * invN - mu * mu;
    float sc = g[c] * rsqrtf(var + 1e-3f);
    scale[c] = sc;
    bias[c] = be[c] - mu * sc;
  }
}

// BN2+ReLU: read Y2 bf16 [65536][128], write f32 d_out.
__global__ __launch_bounds__(256) void bnrelu_out_kernel(
    const unsigned short* __restrict__ Y2, const float* __restrict__ scale,
    const float* __restrict__ bias, float* __restrict__ out) {
  const size_t i = ((size_t)blockIdx.x * 256 + threadIdx.x) * 8;
  const int c0 = (int)(i & 127);
  uint4 v = *(const uint4*)(Y2 + i);
  const f32x4 sA = *(const f32x4*)(scale + c0);
  const f32x4 sB = *(const f32x4*)(scale + c0 + 4);
  const f32x4 bA = *(const f32x4*)(bias + c0);
  const f32x4 bB = *(const f32x4*)(bias + c0 + 4);
  unsigned int w[4] = {v.x, v.y, v.z, v.w};
  f32x4 o0, o1;
#pragma unroll
  for (int q = 0; q < 2; q++) {
    o0[q * 2 + 0] = fmaxf(0.f, fmaf(bf2f((unsigned short)(w[q] & 0xffff)), sA[q * 2 + 0], bA[q * 2 + 0]));
    o0[q * 2 + 1] = fmaxf(0.f, fmaf(bf2f((unsigned short)(w[q] >> 16)),   sA[q * 2 + 1], bA[q * 2 + 1]));
    o1[q * 2 + 0] = fmaxf(0.f, fmaf(bf2f((unsigned short)(w[q + 2] & 0xffff)), sB[q * 2 + 0], bB[q * 2 + 0]));
    o1[q * 2 + 1] = fmaxf(0.f, fmaf(bf2f((unsigned short)(w[q + 2] >> 16)),   sB[q * 2 + 1], bB[q * 2 + 1]));
  }
  *(f32x4*)(out + i) = o0;
  *(f32x4*)(out + i + 4) = o1;
}

// ---------------------------------------------------------------------------
extern "C" void kernel_launch(void* const* d_in, const int* in_sizes, int n_in,
                              void* d_out, int out_size, void* d_ws,
                              size_t ws_size, hipStream_t stream) {
  const float* xyz1 = (const float*)d_in[0];
  const float* points1 = (const float*)d_in[1];
  const float* xyz2 = (const float*)d_in[2];
  const float* points2 = (const float*)d_in[3];
  const float* W0 = (const float*)d_in[4];
  const float* b0 = (const float*)d_in[5];
  const float* g0 = (const float*)d_in[6];
  const float* be0 = (const float*)d_in[7];
  const float* W1 = (const float*)d_in[8];
  const float* b1 = (const float*)d_in[9];
  const float* g1 = (const float*)d_in[10];
  const float* be1 = (const float*)d_in[11];

  char* ws = (char*)d_ws;
  unsigned short* X = (unsigned short*)(ws);              // [65536][384] bf16
  unsigned short* Y2 = (unsigned short*)(ws);             // [65536][128] bf16 (aliases X; X dead after GEMM1)
  unsigned short* Y = (unsigned short*)(ws + 50331648);   // [65536][256] bf16
  // Scratch dead before GEMM1 writes Y — aliased into the Y region:
  unsigned short* P2 = (unsigned short*)(ws + 50331648);  // 8 MB bf16 points2
  float* W3 = (float*)(ws + 50331648 + 8388608);
  int* I3 = (int*)(ws + 50331648 + 8388608 + 786432);
  unsigned short* W0t = (unsigned short*)(ws + 83886080);
  unsigned short* W1t = (unsigned short*)(ws + 84082688);
  float* stats = (float*)(ws + 84148224);
  float* sum1 = stats, *sq1 = stats + 256, *scale1 = stats + 512, *bias1 = stats + 768;
  float* sum2 = stats + 1024, *sq2 = stats + 1152, *scale2 = stats + 1280, *bias2 = stats + 1408;
  float* outF = (float*)d_out;

  hipMemsetAsync(stats, 0, 1536 * sizeof(float), stream);
  prep_kernel<<<4096, 256, 0, stream>>>(W0, W1, points2, W0t, W1t, P2);
  three_nn_kernel<<<dim3(128, 16), 256, 0, stream>>>(xyz1, xyz2, W3, I3);
  interp_concat_kernel<<<2048, 256, 0, stream>>>(points1, P2, W3, I3, X);
  gemm1_kernel<<<512, 512, 0, stream>>>(X, W0t, b0, Y, sum1, sq1);
  bn_fin_kernel<<<1, 256, 0, stream>>>(sum1, sq1, g0, be0, scale1, bias1, 256);
  gemm2_kernel<<<512, 256, 0, stream>>>(Y, W1t, scale1, bias1, b1, Y2, sum2, sq2);
  bn_fin_kernel<<<1, 128, 0, stream>>>(sum2, sq2, g1, be1, scale2, bias2, 128);
  bnrelu_out_kernel<<<4096, 256, 0, stream>>>(Y2, scale2, bias2, outF);
}